// Round 5
// baseline (70.986 us; speedup 1.0000x reference)
//
#include <hip/hip_runtime.h>

// EDeeperGCN: out[e] = relu(cat(x[src],x[dst]) @ W1 + b1) @ W2 + b2
// AB[n] = [x[n]@W1_top + b1 | x[n]@W1_bot]  (fp16, in d_ws)
// out[e] = relu(A[src[e]] + B[dst[e]]) @ W2 + b2
//
// node_AB: round-3-proven structure (fp32 weights, LDS x-tile); xs read as
//          float4 (4x fewer LDS-pipe ops, identical numerics).
// edge_mlp: 8 lanes/edge (each gather instr = 128B contiguous per edge);
//          W2 rows held in 80 h2 VGPRs per lane, loaded once from a plain
//          [64][10] LDS table; ZERO LDS reads in the edge loop.

typedef __fp16 h2 __attribute__((ext_vector_type(2)));
typedef __fp16 h8 __attribute__((ext_vector_type(8)));

#define HID  128
#define TWOH 256
#define OUTD 10
#define NPB  16   // nodes per block, kernel 1
#define EPG  8    // edges per 8-lane group, kernel 2

// ---------------- Kernel 1: AB = [x@W1_top + b1 | x@W1_bot], fp16 output ----------------
__global__ __launch_bounds__(256) void node_AB(
    const float* __restrict__ x,    // [N, 128]
    const float* __restrict__ W1,   // [256, 128]
    const float* __restrict__ b1,   // [128]
    __fp16* __restrict__ AB,        // [N, 256]
    int n_nodes)
{
    __shared__ float xs[NPB][HID];          // 8 KB x-tile
    const int t = threadIdx.x;              // 0..255: output column of AB
    const int node0 = blockIdx.x * NPB;     // 10000 % 16 == 0: tile always full

    const float4* xg = (const float4*)(x + (long)node0 * HID);
    float4* xs4 = (float4*)xs;
#pragma unroll
    for (int i = 0; i < (NPB * HID / 4) / 256; ++i)     // 2 iters, coalesced
        xs4[t + i * 256] = xg[t + i * 256];
    __syncthreads();

    const float* wcol = (t < HID) ? (W1 + t) : (W1 + HID * HID + (t - HID));

    float acc[NPB];
#pragma unroll
    for (int n = 0; n < NPB; ++n) acc[n] = 0.f;

    for (int kb = 0; kb < HID / 4; ++kb) {
        const float w0 = wcol[(long)(4 * kb + 0) * HID];   // coalesced across lanes
        const float w1 = wcol[(long)(4 * kb + 1) * HID];
        const float w2 = wcol[(long)(4 * kb + 2) * HID];
        const float w3 = wcol[(long)(4 * kb + 3) * HID];
#pragma unroll
        for (int n = 0; n < NPB; ++n) {
            const float4 xv = *(const float4*)&xs[n][kb * 4];  // ds_read_b128 broadcast
            float a = acc[n];
            a = fmaf(xv.x, w0, a);
            a = fmaf(xv.y, w1, a);
            a = fmaf(xv.z, w2, a);
            a = fmaf(xv.w, w3, a);
            acc[n] = a;
        }
    }

    const float bias = (t < HID) ? b1[t] : 0.f;
#pragma unroll
    for (int n = 0; n < NPB; ++n) {
        const int node = node0 + n;
        if (node < n_nodes) AB[(long)node * TWOH + t] = (__fp16)(acc[n] + bias);
    }
}

// ---------------- Kernel 2: 8 lanes/edge, register-stationary W2 ----------------
__global__ __launch_bounds__(256) void edge_mlp(
    const __fp16* __restrict__ AB,  // [N, 256]  (row = 32 x 16B chunks)
    const int* __restrict__ ei,     // [2, E]
    const float* __restrict__ W2,   // [128, 10]
    const float* __restrict__ b2,   // [10]
    float* __restrict__ out,        // [E, 10]
    int n_edges)
{
    // Plain k-pair-major W2 table: w2s[kp][j] = (W2[2kp][j], W2[2kp+1][j])
    __shared__ h2 w2s[HID / 2][OUTD];
    const int t = threadIdx.x;
    for (int m = t; m < (HID / 2) * OUTD; m += 256) {
        const int kp = m / OUTD, j = m % OUTD;
        h2 v;
        v.x = (__fp16)W2[(2 * kp) * OUTD + j];
        v.y = (__fp16)W2[(2 * kp + 1) * OUTD + j];
        w2s[kp][j] = v;
    }
    __syncthreads();

    const int lane = t & 63;
    const int ll = lane & 7;         // lane within 8-lane group
    const int g  = lane >> 3;        // group 0..7 within wave
    const int wv = t >> 6;           // wave within block

    // Lane's 8 W2 row-pairs -> 80 h2 registers (one-time LDS read; 2-way
    // bank aliasing at most = free). Row r holds kp = (r>>2)*32 + 4*ll + (r&3),
    // i.e. k = {8*ll + 2*(r&3)} (+64 for r>=4) -- matches s0/s1 pairs below.
    h2 wreg[8][OUTD];
#pragma unroll
    for (int r = 0; r < 8; ++r) {
        const int kp = (r >> 2) * 32 + 4 * ll + (r & 3);
#pragma unroll
        for (int j = 0; j < OUTD; ++j) wreg[r][j] = w2s[kp][j];
    }

    // lane's output pair (j = 2*ll, 2*ll+1), lanes 0..4 only
    float bj0 = 0.f, bj1 = 0.f;
    if (ll < 5) { bj0 = b2[2 * ll]; bj1 = b2[2 * ll + 1]; }

    const h8* __restrict__ ABv = (const h8*)AB;   // row n: chunks n*32..n*32+31
    const long ebase = (long)blockIdx.x * 256 + wv * 64 + g;

#pragma unroll
    for (int i = 0; i < EPG; ++i) {
        const long e = ebase + (long)i * 8;
        if (e >= n_edges) continue;
        const int sn = ei[e];                       // 8 lanes same addr -> broadcast
        const int dn = ei[(long)n_edges + e];

        const long ab = (long)sn * 32, bb = (long)dn * 32;
        const h8 a0 = ABv[ab + ll];          // A: k = 8*ll .. 8*ll+7
        const h8 a1 = ABv[ab + 8 + ll];      // A: k = 64+8*ll .. +7
        const h8 c0 = ABv[bb + 16 + ll];     // B: same k ranges
        const h8 c1 = ABv[bb + 24 + ll];     // (8 lanes = 128B contiguous/instr)

        const h8 z = {0, 0, 0, 0, 0, 0, 0, 0};
        const h8 s0 = __builtin_elementwise_max(a0 + c0, z);
        const h8 s1 = __builtin_elementwise_max(a1 + c1, z);

        float acc[OUTD];
#pragma unroll
        for (int j = 0; j < OUTD; ++j) acc[j] = 0.f;

#pragma unroll
        for (int p = 0; p < 4; ++p) {
            h2 hp0; hp0.x = s0[2 * p]; hp0.y = s0[2 * p + 1];  // k = 8ll+2p, +1
            h2 hp1; hp1.x = s1[2 * p]; hp1.y = s1[2 * p + 1];  // k = 64+8ll+2p, +1
#pragma unroll
            for (int j = 0; j < OUTD; ++j)
                acc[j] = __builtin_amdgcn_fdot2(hp0, wreg[p][j], acc[j], false);
#pragma unroll
            for (int j = 0; j < OUTD; ++j)
                acc[j] = __builtin_amdgcn_fdot2(hp1, wreg[4 + p][j], acc[j], false);
        }

        // reduce across the 8-lane group (xor 1,2,4): all lanes get full sums
#pragma unroll
        for (int j = 0; j < OUTD; ++j) {
            acc[j] += __shfl_xor(acc[j], 1);
            acc[j] += __shfl_xor(acc[j], 2);
            acc[j] += __shfl_xor(acc[j], 4);
        }

        if (ll < 5) {   // lane ll stores outputs (2*ll, 2*ll+1): contiguous/wave
            const float v0 = (ll == 0) ? acc[0] : (ll == 1) ? acc[2]
                           : (ll == 2) ? acc[4] : (ll == 3) ? acc[6] : acc[8];
            const float v1 = (ll == 0) ? acc[1] : (ll == 1) ? acc[3]
                           : (ll == 2) ? acc[5] : (ll == 3) ? acc[7] : acc[9];
            *(float2*)(out + e * OUTD + 2 * ll) = make_float2(v0 + bj0, v1 + bj1);
        }
    }
}

extern "C" void kernel_launch(void* const* d_in, const int* in_sizes, int n_in,
                              void* d_out, int out_size, void* d_ws, size_t ws_size,
                              hipStream_t stream) {
    const float* x  = (const float*)d_in[0];
    const int*   ei = (const int*)d_in[1];
    const float* W1 = (const float*)d_in[2];
    const float* b1 = (const float*)d_in[3];
    const float* W2 = (const float*)d_in[4];
    const float* b2 = (const float*)d_in[5];
    float* out = (float*)d_out;

    const int n_nodes = in_sizes[0] / HID;          // 10000
    const int n_edges = in_sizes[1] / 2;            // 640000

    __fp16* AB = (__fp16*)d_ws;                     // [n_nodes, 256] fp16 = 5.12 MB

    node_AB<<<(n_nodes + NPB - 1) / NPB, 256, 0, stream>>>(x, W1, b1, AB, n_nodes);

    edge_mlp<<<(n_edges + 255) / 256, 256, 0, stream>>>(AB, ei, W2, b2, out, n_edges);
}

// Round 6
// 70.605 us; speedup vs baseline: 1.0054x; 1.0054x over previous
//
#include <hip/hip_runtime.h>

// EDeeperGCN: out[e] = relu(cat(x[src],x[dst]) @ W1 + b1) @ W2 + b2
// AB[n] = [x[n]@W1_top + b1 | x[n]@W1_bot]  (f16, in d_ws)
// out[e] = relu(A[src[e]] + B[dst[e]]) @ W2 + b2
//
// Both GEMMs on the MFMA pipe (mfma_f32_16x16x32_f16).
// Fragment convention (self-consistent for A and B, permutation-invariant):
//   lane = 16*g + r (r=lane&15, g=lane>>4)
//   A: row r, k-slots {32*st + 8g .. +7} per step st
//   B: col r, same k-slots
//   C/D (HW-verified m89): col = lane&15, row = (lane>>4)*4 + reg
// edge_mlp: 16 edges/wave/iter; gather = one aligned 64B line per edge per
// load instr; W2 fragment lives in 16 VGPRs; zero LDS, zero shuffles.

typedef _Float16 f16;
typedef _Float16 f16x8 __attribute__((ext_vector_type(8)));
typedef float    f32x4 __attribute__((ext_vector_type(4)));

#define HID  128
#define TWOH 256
#define OUTD 10

// ---------------- Kernel 1: AB = x @ W1cat + [b1|0], f16 out, MFMA ----------------
// Block = 16 nodes x 256 cols; wave wv covers cols 64*wv .. +63 (4 col-tiles).
__global__ __launch_bounds__(256) void node_AB(
    const float* __restrict__ x,    // [N, 128]
    const float* __restrict__ W1,   // [256, 128]
    const float* __restrict__ b1,   // [128]
    f16* __restrict__ AB,           // [N, 256]
    int n_nodes)
{
    const int t = threadIdx.x;
    const int lane = t & 63;
    const int r = lane & 15, g = lane >> 4;
    const int wv = t >> 6;
    const int n0 = blockIdx.x * 16;
    const int c0 = wv * 64;

    // B-fragments: W1cat[k][c], c = c0 + 16*ct + r; k = 32*st + 8*g + j
    // W1cat[k][c] = W1[k][c] (c<128)  |  W1[128+k][c-128] (c>=128)
    f16x8 w1f[4][4];
#pragma unroll
    for (int ct = 0; ct < 4; ++ct) {
        const int c = c0 + ct * 16 + r;
        const float* wp = (c < HID) ? (W1 + c) : (W1 + HID * HID + (c - HID));
#pragma unroll
        for (int st = 0; st < 4; ++st) {
            f16x8 v;
#pragma unroll
            for (int j = 0; j < 8; ++j)
                v[j] = (f16)wp[(long)(st * 32 + g * 8 + j) * HID];
            w1f[ct][st] = v;
        }
    }

    const int xrow = (n0 + r < n_nodes) ? (n0 + r) : (n_nodes - 1);
    f32x4 acc[4] = {{0,0,0,0},{0,0,0,0},{0,0,0,0},{0,0,0,0}};
#pragma unroll
    for (int st = 0; st < 4; ++st) {
        const float* xp = x + (long)xrow * HID + st * 32 + g * 8;
        const float4 x0 = *(const float4*)xp;        // 16B-aligned
        const float4 x1 = *(const float4*)(xp + 4);
        f16x8 a;
        a[0] = (f16)x0.x; a[1] = (f16)x0.y; a[2] = (f16)x0.z; a[3] = (f16)x0.w;
        a[4] = (f16)x1.x; a[5] = (f16)x1.y; a[6] = (f16)x1.z; a[7] = (f16)x1.w;
#pragma unroll
        for (int ct = 0; ct < 4; ++ct)
            acc[ct] = __builtin_amdgcn_mfma_f32_16x16x32_f16(a, w1f[ct][st], acc[ct], 0, 0, 0);
    }

#pragma unroll
    for (int ct = 0; ct < 4; ++ct) {
        const int c = c0 + ct * 16 + r;
        const float bias = (c < HID) ? b1[c] : 0.f;
#pragma unroll
        for (int q = 0; q < 4; ++q) {
            const int node = n0 + g * 4 + q;         // D row = node-within-tile
            if (node < n_nodes)
                AB[(long)node * TWOH + c] = (f16)(acc[ct][q] + bias);
        }
    }
}

// ---------------- Kernel 2: edge gather + relu + [128x10] GEMM, MFMA ----------------
// Block = 256 edges (4 waves x 4 iters x 16 edges). Zero LDS.
__global__ __launch_bounds__(256) void edge_mlp(
    const f16* __restrict__ AB,     // [N, 256] = 32 f16x8 chunks per row
    const int* __restrict__ ei,     // [2, E]
    const float* __restrict__ W2,   // [128, 10]
    const float* __restrict__ b2,   // [10]
    float* __restrict__ out,        // [E, 10]
    int n_edges)
{
    const int t = threadIdx.x;
    const int lane = t & 63;
    const int r = lane & 15, g = lane >> 4;
    const int wv = t >> 6;

    // W2 B-fragment in 16 VGPRs: col r (zeros for r>=10); k = 32*st + 8g + j
    const bool cok = (r < OUTD);
    const int cw = cok ? r : 0;
    f16x8 w2f[4];
#pragma unroll
    for (int st = 0; st < 4; ++st) {
        f16x8 v;
#pragma unroll
        for (int j = 0; j < 8; ++j) {
            const float w = W2[(long)(st * 32 + g * 8 + j) * OUTD + cw];
            v[j] = cok ? (f16)w : (f16)0.f;
        }
        w2f[st] = v;
    }
    const float bj = cok ? b2[r] : 0.f;

    const f16x8* __restrict__ ABv = (const f16x8*)AB;
    const long eb = (long)blockIdx.x * 256 + wv * 64;

#pragma unroll
    for (int it = 0; it < 4; ++it) {
        const long e = eb + it * 16 + r;
        const long ec = (e < n_edges) ? e : (n_edges - 1);
        const int sn = ei[ec];                       // 16 dwords, 4-way broadcast
        const int dn = ei[(long)n_edges + ec];

        f32x4 acc = {0, 0, 0, 0};
#pragma unroll
        for (int st = 0; st < 4; ++st) {
            // A-half chunk (32*st+8g)/8 = 4*st+g ; B-half +16. Four lanes
            // (g=0..3) of an edge cover one aligned 64B line per instr.
            const f16x8 a = ABv[(long)sn * 32 + st * 4 + g];
            const f16x8 c = ABv[(long)dn * 32 + 16 + st * 4 + g];
            f16x8 s = a + c;                         // v_pk_add_f16
            const f16x8 z = {0, 0, 0, 0, 0, 0, 0, 0};
            s = __builtin_elementwise_max(s, z);     // relu
            acc = __builtin_amdgcn_mfma_f32_16x16x32_f16(s, w2f[st], acc, 0, 0, 0);
        }

        if (cok) {                                   // D: col r = output j, rows = edges
            const long er = eb + it * 16 + g * 4;
#pragma unroll
            for (int q = 0; q < 4; ++q) {
                const long ee = er + q;
                if (ee < n_edges)
                    out[ee * OUTD + r] = acc[q] + bj;
            }
        }
    }
}

extern "C" void kernel_launch(void* const* d_in, const int* in_sizes, int n_in,
                              void* d_out, int out_size, void* d_ws, size_t ws_size,
                              hipStream_t stream) {
    const float* x  = (const float*)d_in[0];
    const int*   ei = (const int*)d_in[1];
    const float* W1 = (const float*)d_in[2];
    const float* b1 = (const float*)d_in[3];
    const float* W2 = (const float*)d_in[4];
    const float* b2 = (const float*)d_in[5];
    float* out = (float*)d_out;

    const int n_nodes = in_sizes[0] / HID;          // 10000
    const int n_edges = in_sizes[1] / 2;            // 640000

    f16* AB = (f16*)d_ws;                           // [n_nodes, 256] f16 = 5.12 MB

    node_AB<<<(n_nodes + 15) / 16, 256, 0, stream>>>(x, W1, b1, AB, n_nodes);

    edge_mlp<<<(n_edges + 255) / 256, 256, 0, stream>>>(AB, ei, W2, b2, out, n_edges);
}

// Round 7
// 66.581 us; speedup vs baseline: 1.0662x; 1.0604x over previous
//
#include <hip/hip_runtime.h>

// EDeeperGCN: out[e] = relu(cat(x[src],x[dst]) @ W1 + b1) @ W2 + b2
// AB[n] = [x[n]@W1_top + b1 | x[n]@W1_bot]  (f16, in d_ws)
// out[e] = relu(A[src[e]] + B[dst[e]]) @ W2 + b2
//
// Both GEMMs on mfma_f32_16x16x32_f16 with the round-6-proven fragment map:
//   lane = 16*g + r;  A: row r, k = 32*st + 8g + j;  B: col r, same k
//   C/D (HW, m89): col = lane&15, row = (lane>>4)*4 + reg
// edge_mlp: 8 iters x 16 edges per wave, explicit 1-deep double-buffered
//   gathers (line-perfect: 4 lanes x 16B = one 64B line per edge per instr),
//   LDS-staged full-line float4 stores (no read-modify-write on out).
// node_AB: weights from pre-transposed f16 W1T (one b128 per fragment),
//   tile-strided to amortize the weight load.

typedef _Float16 f16;
typedef _Float16 f16x8 __attribute__((ext_vector_type(8)));
typedef float    f32x4 __attribute__((ext_vector_type(4)));

#define HID  128
#define TWOH 256
#define OUTD 10

// ---------------- Kernel 0: W1T[c][k] = W1cat[k][c], f16 [256][128] ----------------
__global__ __launch_bounds__(256) void w1_transpose(
    const float* __restrict__ W1,   // [256, 128]
    f16* __restrict__ W1T)          // [256, 128] (c-major)
{
    const int idx = blockIdx.x * 256 + threadIdx.x;   // 32768 elements
    const int c = idx >> 7, k = idx & 127;
    const float v = (c < HID) ? W1[k * HID + c]
                              : W1[(HID + k) * HID + (c - HID)];
    W1T[idx] = (f16)v;                                 // coalesced f16 writes
}

// ---------------- Kernel 1: AB = x @ W1cat + [b1|0], f16 out, MFMA ----------------
__global__ __launch_bounds__(256) void node_AB(
    const float* __restrict__ x,    // [N, 128]
    const f16* __restrict__ W1T,    // [256, 128] c-major
    const float* __restrict__ b1,   // [128]
    f16* __restrict__ AB,           // [N, 256]
    int n_nodes, int n_tiles)
{
    const int t = threadIdx.x;
    const int lane = t & 63;
    const int r = lane & 15, g = lane >> 4;
    const int wv = t >> 6;
    const int c0 = wv * 64;

    // B-fragments: one b128 load each (j contiguous in W1T); 16 total.
    f16x8 w1f[4][4];
    float bias[4];
#pragma unroll
    for (int ct = 0; ct < 4; ++ct) {
        const int c = c0 + ct * 16 + r;
        bias[ct] = (c < HID) ? b1[c] : 0.f;
#pragma unroll
        for (int st = 0; st < 4; ++st)
            w1f[ct][st] = *(const f16x8*)(W1T + (long)c * HID + st * 32 + g * 8);
    }

    for (int tile = blockIdx.x; tile < n_tiles; tile += gridDim.x) {
        const int n0 = tile * 16;
        const int xrow = (n0 + r < n_nodes) ? (n0 + r) : (n_nodes - 1);

        f32x4 acc[4] = {{0,0,0,0},{0,0,0,0},{0,0,0,0},{0,0,0,0}};
#pragma unroll
        for (int st = 0; st < 4; ++st) {
            const float* xp = x + (long)xrow * HID + st * 32 + g * 8;
            const float4 x0 = *(const float4*)xp;
            const float4 x1 = *(const float4*)(xp + 4);
            f16x8 a;
            a[0] = (f16)x0.x; a[1] = (f16)x0.y; a[2] = (f16)x0.z; a[3] = (f16)x0.w;
            a[4] = (f16)x1.x; a[5] = (f16)x1.y; a[6] = (f16)x1.z; a[7] = (f16)x1.w;
#pragma unroll
            for (int ct = 0; ct < 4; ++ct)
                acc[ct] = __builtin_amdgcn_mfma_f32_16x16x32_f16(a, w1f[ct][st], acc[ct], 0, 0, 0);
        }

#pragma unroll
        for (int ct = 0; ct < 4; ++ct) {
            const int c = c0 + ct * 16 + r;
#pragma unroll
            for (int q = 0; q < 4; ++q) {
                const int node = n0 + g * 4 + q;      // D row = node-within-tile
                if (node < n_nodes)
                    AB[(long)node * TWOH + c] = (f16)(acc[ct][q] + bias[ct]);
            }
        }
    }
}

// ---------------- Kernel 2: edge gather + relu + [128x10] GEMM, MFMA ----------------
// Block = 4 waves x 128 edges = 512 edges. 1-deep pipelined gathers.
__global__ __launch_bounds__(256) void edge_mlp(
    const f16* __restrict__ AB,     // [N, 256] = 32 f16x8 chunks per row
    const int* __restrict__ ei,     // [2, E]
    const float* __restrict__ W2,   // [128, 10]
    const float* __restrict__ b2,   // [10]
    float* __restrict__ out,        // [E, 10]
    int n_edges)
{
    __shared__ float stage[4][160];                    // 640B per wave
    const int t = threadIdx.x;
    const int lane = t & 63;
    const int r = lane & 15, g = lane >> 4;
    const int wv = t >> 6;

    // W2 B-fragment in 16 VGPRs: col r (zeros for r>=10); k = 32*st + 8g + j
    const bool cok = (r < OUTD);
    const int cw = cok ? r : 0;
    f16x8 w2f[4];
#pragma unroll
    for (int st = 0; st < 4; ++st) {
        f16x8 v;
#pragma unroll
        for (int j = 0; j < 8; ++j) {
            const float w = W2[(long)(st * 32 + g * 8 + j) * OUTD + cw];
            v[j] = cok ? (f16)w : (f16)0.f;
        }
        w2f[st] = v;
    }
    const float bj = cok ? b2[r] : 0.f;

    const f16x8* __restrict__ ABv = (const f16x8*)AB;
    const long eb = (long)blockIdx.x * 512 + wv * 128;

    // all 8 iterations' indices up front (4-way broadcast across g)
    int sn[8], dn[8];
#pragma unroll
    for (int it = 0; it < 8; ++it) {
        const long e = eb + it * 16 + r;
        const long ec = (e < n_edges) ? e : (n_edges - 1);
        sn[it] = ei[ec];
        dn[it] = ei[(long)n_edges + ec];
    }

    // double-buffered gathers; fully unrolled -> all indices compile-time
    f16x8 pa[2][4], pc[2][4];
#pragma unroll
    for (int st = 0; st < 4; ++st) {
        pa[0][st] = ABv[(long)sn[0] * 32 + st * 4 + g];
        pc[0][st] = ABv[(long)dn[0] * 32 + 16 + st * 4 + g];
    }

#pragma unroll
    for (int it = 0; it < 8; ++it) {
        const int cur = it & 1, nxt = cur ^ 1;
        if (it < 7) {
            const long an = (long)sn[it + 1] * 32, bn = (long)dn[it + 1] * 32;
#pragma unroll
            for (int st = 0; st < 4; ++st) {
                pa[nxt][st] = ABv[an + st * 4 + g];
                pc[nxt][st] = ABv[bn + 16 + st * 4 + g];
            }
        }

        const f16x8 z = {0, 0, 0, 0, 0, 0, 0, 0};
        f32x4 acc = {0, 0, 0, 0};
#pragma unroll
        for (int st = 0; st < 4; ++st) {
            const f16x8 s = __builtin_elementwise_max(pa[cur][st] + pc[cur][st], z);
            acc = __builtin_amdgcn_mfma_f32_16x16x32_f16(s, w2f[st], acc, 0, 0, 0);
        }

        const long base = eb + (long)it * 16;
        if (base + 16 <= n_edges) {
            // transpose via wave-private LDS slab, then one full-line store
            if (cok) {
#pragma unroll
                for (int q = 0; q < 4; ++q)
                    stage[wv][(g * 4 + q) * OUTD + r] = acc[q] + bj;   // D row = edge
            }
            __builtin_amdgcn_wave_barrier();       // order ds_write -> ds_read
            if (lane < 40) {
                const float4 vv = *(const float4*)&stage[wv][lane * 4];
                *(float4*)(out + base * OUTD + lane * 4) = vv;   // 640B contiguous
            }
            __builtin_amdgcn_wave_barrier();       // order read -> next iter's write
        } else if (cok) {                          // generic tail (unused at E=640000)
#pragma unroll
            for (int q = 0; q < 4; ++q) {
                const long ee = base + g * 4 + q;
                if (ee < n_edges) out[ee * OUTD + r] = acc[q] + bj;
            }
        }
    }
}

extern "C" void kernel_launch(void* const* d_in, const int* in_sizes, int n_in,
                              void* d_out, int out_size, void* d_ws, size_t ws_size,
                              hipStream_t stream) {
    const float* x  = (const float*)d_in[0];
    const int*   ei = (const int*)d_in[1];
    const float* W1 = (const float*)d_in[2];
    const float* b1 = (const float*)d_in[3];
    const float* W2 = (const float*)d_in[4];
    const float* b2 = (const float*)d_in[5];
    float* out = (float*)d_out;

    const int n_nodes = in_sizes[0] / HID;          // 10000
    const int n_edges = in_sizes[1] / 2;            // 640000
    const int n_tiles = (n_nodes + 15) / 16;        // 625

    f16* AB  = (f16*)d_ws;                          // [n_nodes, 256] f16 = 5.12 MB
    f16* W1T = AB + (long)n_nodes * TWOH;           // 64 KB, 16B-aligned

    w1_transpose<<<(TWOH * HID) / 256, 256, 0, stream>>>(W1, W1T);

    int nb = (n_tiles + 1) / 2;                     // 2 tiles/block
    node_AB<<<nb, 256, 0, stream>>>(x, W1T, b1, AB, n_nodes, n_tiles);

    edge_mlp<<<(n_edges + 511) / 512, 256, 0, stream>>>(AB, ei, W2, b2, out, n_edges);
}